// Round 5
// baseline (288.810 us; speedup 1.0000x reference)
//
#include <hip/hip_runtime.h>
#include <hip/hip_bf16.h>

typedef float f32x4 __attribute__((ext_vector_type(4)));
typedef __bf16 bf16x8 __attribute__((ext_vector_type(8)));
typedef unsigned short us4 __attribute__((ext_vector_type(4)));

constexpr int B = 8, L = 1024, S = 1024, H = 8;
constexpr float LOG2E = 1.4426950408889634f;
// 1/sqrt(32) * log2(e): exp(x) == exp2(x*log2e); folded into Q-scale and mask.
constexpr float SCALE_Q = 0.17677669529663687f * 1.4426950408889634f;

__device__ __forceinline__ unsigned short bfbits(float x) {
  return __builtin_bit_cast(unsigned short, (__bf16)x);
}
__device__ __forceinline__ float b2f(unsigned short u) {
  return __builtin_bit_cast(float, (unsigned int)u << 16);
}

// ---------------------------------------------------------------------------
// Kernel 0: maskT[b][lt][s][16] = mask[b][lt*16+r][s] * LOG2E, bf16.
// 16x64 tile transpose via LDS; coalesced f32 reads, coalesced 8B writes.
// ---------------------------------------------------------------------------
__global__ __launch_bounds__(256) void prep_mask_kernel(
    const float* __restrict__ mask, __bf16* __restrict__ maskT)
{
  __shared__ float tile[16][65];
  const int tid = threadIdx.x;
  const int sc = blockIdx.x, lt = blockIdx.y, b = blockIdx.z;
  const int s0 = sc * 64;
  const int q = tid >> 6, sl = tid & 63;
  #pragma unroll
  for (int rr = 0; rr < 4; ++rr) {
    int row = q * 4 + rr;
    tile[row][sl] = mask[((size_t)(b * 1024 + lt * 16 + row)) * 1024 + s0 + sl] * LOG2E;
  }
  __syncthreads();
  const int sl2 = tid >> 2, rq = (tid & 3) * 4;
  us4 o;
  #pragma unroll
  for (int j = 0; j < 4; ++j) o[j] = bfbits(tile[rq + j][sl2]);
  *reinterpret_cast<us4*>(maskT + (((size_t)(b * 64 + lt)) * 1024 + s0 + sl2) * 16 + rq) = o;
}

// ---------------------------------------------------------------------------
// Kernel 1: five projection GEMMs (M=8192,N=256,K=256), y = x@W^T, bf16 out.
// A,W staged via LDS (coalesced f32 loads, one-time bf16 convert).
//   z=0..3: [B,H,T,32]   (q_self*SCALE_Q, q_other*SCALE_Q, k_self, k_other)
//   z=4   : [B,H,S/32,32vd,32s] tiles (v, transposed via LDS)
// ---------------------------------------------------------------------------
__global__ __launch_bounds__(256) void proj_kernel(
    const float* __restrict__ q, const float* __restrict__ k, const float* __restrict__ v,
    const float* __restrict__ wqs, const float* __restrict__ wqo,
    const float* __restrict__ wks, const float* __restrict__ wko,
    const float* __restrict__ wv,
    __bf16* __restrict__ qs, __bf16* __restrict__ qo,
    __bf16* __restrict__ ksl, __bf16* __restrict__ kol,
    __bf16* __restrict__ vht)
{
  const int proj = blockIdx.z;
  const float* X; const float* W;
  if (proj == 0)      { X = q; W = wqs; }
  else if (proj == 1) { X = q; W = wqo; }
  else if (proj == 2) { X = k; W = wks; }
  else if (proj == 3) { X = k; W = wko; }
  else                { X = v; W = wv;  }

  __shared__ __align__(16) char smem[2 * 64 * 264 * 2];
  __bf16 (*At)[264] = (__bf16(*)[264])smem;
  __bf16 (*Wt)[264] = (__bf16(*)[264])(smem + 64 * 264 * 2);
  float  (*ct)[65]  = (float(*)[65])smem;   // aliases At; used only post-sync (proj==4)

  const int tid = threadIdx.x;
  const int m0 = blockIdx.y * 64, n0 = blockIdx.x * 64;

  for (int i = tid; i < 4096; i += 256) {
    int row = i >> 6, c4 = (i & 63) << 2;
    float4 a  = *reinterpret_cast<const float4*>(X + (size_t)(m0 + row) * 256 + c4);
    float4 ww = *reinterpret_cast<const float4*>(W + (size_t)(n0 + row) * 256 + c4);
    us4 ap, wp;
    ap[0] = bfbits(a.x);  ap[1] = bfbits(a.y);  ap[2] = bfbits(a.z);  ap[3] = bfbits(a.w);
    wp[0] = bfbits(ww.x); wp[1] = bfbits(ww.y); wp[2] = bfbits(ww.z); wp[3] = bfbits(ww.w);
    *reinterpret_cast<us4*>(&At[row][c4]) = ap;
    *reinterpret_cast<us4*>(&Wt[row][c4]) = wp;
  }
  __syncthreads();

  const int w = tid >> 6, lane = tid & 63;
  const int cl = lane & 15, g = lane >> 4;

  f32x4 zf = {0.f, 0.f, 0.f, 0.f};
  f32x4 acc[4] = {zf, zf, zf, zf};
  #pragma unroll
  for (int kk = 0; kk < 8; ++kk) {
    bf16x8 af = *reinterpret_cast<const bf16x8*>(&At[w * 16 + cl][kk * 32 + g * 8]);
    #pragma unroll
    for (int nt = 0; nt < 4; ++nt) {
      bf16x8 bfr = *reinterpret_cast<const bf16x8*>(&Wt[nt * 16 + cl][kk * 32 + g * 8]);
      acc[nt] = __builtin_amdgcn_mfma_f32_16x16x32_bf16(af, bfr, acc[nt], 0, 0, 0);
    }
  }
  if (proj < 2) {
    #pragma unroll
    for (int nt = 0; nt < 4; ++nt)
      #pragma unroll
      for (int r = 0; r < 4; ++r) acc[nt][r] *= SCALE_Q;
  }

  if (proj < 4) {
    __bf16* Y = (proj == 0) ? qs : (proj == 1) ? qo : (proj == 2) ? ksl : kol;
    #pragma unroll
    for (int nt = 0; nt < 4; ++nt) {
      int n = n0 + nt * 16 + cl;
      int h = n >> 5, hd = n & 31;
      #pragma unroll
      for (int r = 0; r < 4; ++r) {
        int m = m0 + w * 16 + g * 4 + r;
        int bb = m >> 10, t = m & 1023;
        Y[(((size_t)(bb * H + h)) * 1024 + t) * 32 + hd] = (__bf16)acc[nt][r];
      }
    }
  } else {
    __syncthreads();   // At/Wt dead; reuse as ct
    #pragma unroll
    for (int nt = 0; nt < 4; ++nt)
      #pragma unroll
      for (int r = 0; r < 4; ++r)
        ct[w * 16 + g * 4 + r][nt * 16 + cl] = acc[nt][r];
    __syncthreads();
    int n_local = tid >> 2;          // 0..63 (h*32+vd within n-block)
    int sc = (tid & 3) << 4;         // 0,16,32,48 s-chunk
    int n = n0 + n_local;
    int h = n >> 5, vd = n & 31;
    int bb = m0 >> 10;
    int sbase = m0 & 1023;
    int t32 = (sbase + sc) >> 5, off = (sbase + sc) & 31;
    __bf16* dst = vht + ((((size_t)(bb * H + h)) * 32 + t32)) * 1024 + vd * 32 + off;
    bf16x8 o0, o1;
    #pragma unroll
    for (int j = 0; j < 8; ++j) o0[j] = (__bf16)ct[sc + j][n_local];
    #pragma unroll
    for (int j = 0; j < 8; ++j) o1[j] = (__bf16)ct[sc + 8 + j][n_local];
    *reinterpret_cast<bf16x8*>(dst) = o0;
    *reinterpret_cast<bf16x8*>(dst + 8) = o1;
  }
}

// ---------------------------------------------------------------------------
// Kernel 2: agent-aware attention. Block = (b, 16 q-rows, head-group of 2).
// 4 waves, wave w owns s in [w*256, w*256+256). One barrier per head.
// Logits are in log2 domain (SCALE_Q and maskT carry log2e); p = exp2(lg).
// Unnormalized exp written bf16 to pbuf in the QK loop; normalization applied
// during PV readback (which also accumulates the att_mean partial).
// ---------------------------------------------------------------------------
__global__ __launch_bounds__(256) void attn_kernel(
    const __bf16* __restrict__ qs, const __bf16* __restrict__ qo,
    const __bf16* __restrict__ ksl, const __bf16* __restrict__ kol,
    const __bf16* __restrict__ vht,
    const int* __restrict__ qid, const int* __restrict__ kid,
    const __bf16* __restrict__ maskT,
    float* __restrict__ out_part, __bf16* __restrict__ att_part)
{
  const int b = blockIdx.y;
  const int lt = blockIdx.x;
  const int l0 = lt * 16;
  const int hg = blockIdx.z;           // 0..3, 2 heads each
  const int tid = threadIdx.x;
  const int w = tid >> 6, lane = tid & 63;
  const int cl = lane & 15, g = lane >> 4;
  const int sw = w * 256;

  __shared__ __align__(16) __bf16 pbuf[4][16][264];
  __shared__ float redsum[2][4][16];

  int qid_r[4];
  #pragma unroll
  for (int r = 0; r < 4; ++r) qid_r[r] = qid[b * L + l0 + g * 4 + r];
  int kid_st[16];
  #pragma unroll
  for (int st = 0; st < 16; ++st) kid_st[st] = kid[b * S + sw + st * 16 + cl];

  // coalesced maskT loads: 8 B/lane, wave covers contiguous 512 B per st
  us4 mreg[16];
  {
    const __bf16* mbase = maskT + ((size_t)(b * 64 + lt)) * 16384 + (size_t)(sw + cl) * 16 + g * 4;
    #pragma unroll
    for (int st = 0; st < 16; ++st)
      mreg[st] = *reinterpret_cast<const us4*>(mbase + st * 256);
  }

  f32x4 zf = {0.f, 0.f, 0.f, 0.f};
  float att_acc[8][8];
  #pragma unroll
  for (int kt = 0; kt < 8; ++kt)
    #pragma unroll
    for (int j = 0; j < 8; ++j) att_acc[kt][j] = 0.f;

  const size_t PSZ = (size_t)B * L * 256;

  for (int hi = 0; hi < 2; ++hi) {
    const int h = hg * 2 + hi;
    const int par = hi;
    const size_t hb = ((size_t)(b * H + h)) * 1024;

    bf16x8 qsf = *reinterpret_cast<const bf16x8*>(qs + (hb + l0 + cl) * 32 + g * 8);
    bf16x8 qof = *reinterpret_cast<const bf16x8*>(qo + (hb + l0 + cl) * 32 + g * 8);
    const __bf16* kb1 = ksl + (hb + sw) * 32;
    const __bf16* kb2 = kol + (hb + sw) * 32;

    float rsum[4] = {0.f, 0.f, 0.f, 0.f};
    #pragma unroll
    for (int st = 0; st < 16; ++st) {
      bf16x8 kf1 = *reinterpret_cast<const bf16x8*>(kb1 + st * 512 + cl * 32 + g * 8);
      bf16x8 kf2 = *reinterpret_cast<const bf16x8*>(kb2 + st * 512 + cl * 32 + g * 8);
      f32x4 as = __builtin_amdgcn_mfma_f32_16x16x32_bf16(qsf, kf1, zf, 0, 0, 0);
      f32x4 ao = __builtin_amdgcn_mfma_f32_16x16x32_bf16(qof, kf2, zf, 0, 0, 0);
      int kc = kid_st[st];
      #pragma unroll
      for (int r = 0; r < 4; ++r) {
        float lg = ((qid_r[r] == kc) ? as[r] : ao[r]) + b2f(mreg[st][r]);
        float p = __builtin_amdgcn_exp2f(fminf(lg, 86.0f));
        pbuf[w][g * 4 + r][st * 16 + cl] = (__bf16)p;
        rsum[r] += p;
      }
    }

    // row-sum across cl lanes, then across waves
    #pragma unroll
    for (int r = 0; r < 4; ++r) {
      float sv = rsum[r];
      sv += __shfl_xor(sv, 1); sv += __shfl_xor(sv, 2);
      sv += __shfl_xor(sv, 4); sv += __shfl_xor(sv, 8);
      rsum[r] = sv;
    }
    if (cl == 0) {
      #pragma unroll
      for (int r = 0; r < 4; ++r) redsum[par][w][g * 4 + r] = rsum[r];
    }
    __syncthreads();
    float zrow = redsum[par][0][cl] + redsum[par][1][cl] +
                 redsum[par][2][cl] + redsum[par][3][cl];
    float inv_cl = 1.0f / zrow;
    float invq[4];
    #pragma unroll
    for (int r = 0; r < 4; ++r) invq[r] = __shfl(inv_cl, g * 4 + r);

    // PV + att accumulation (reads own wave's pbuf only; no barrier needed)
    f32x4 oa0 = zf, oa1 = zf;
    const __bf16* vb = vht + ((size_t)(b * H + h)) * 32 * 1024 + (size_t)w * 8 * 1024;
    #pragma unroll
    for (int kt = 0; kt < 8; ++kt) {
      bf16x8 pa = *reinterpret_cast<const bf16x8*>(&pbuf[w][cl][kt * 32 + g * 8]);
      #pragma unroll
      for (int j = 0; j < 8; ++j) att_acc[kt][j] += (float)pa[j] * inv_cl;
      bf16x8 v0 = *reinterpret_cast<const bf16x8*>(vb + kt * 1024 + cl * 32 + g * 8);
      bf16x8 v1 = *reinterpret_cast<const bf16x8*>(vb + kt * 1024 + 512 + cl * 32 + g * 8);
      oa0 = __builtin_amdgcn_mfma_f32_16x16x32_bf16(pa, v0, oa0, 0, 0, 0);
      oa1 = __builtin_amdgcn_mfma_f32_16x16x32_bf16(pa, v1, oa1, 0, 0, 0);
    }
    float* op = out_part + (size_t)w * PSZ + ((size_t)(b * 1024 + l0)) * 256 + h * 32;
    #pragma unroll
    for (int r = 0; r < 4; ++r) {
      op[(size_t)(g * 4 + r) * 256 + cl]      = oa0[r] * invq[r];
      op[(size_t)(g * 4 + r) * 256 + cl + 16] = oa1[r] * invq[r];
    }
  }

  // att partial (sum of this head-group's 2 heads, /8) -> bf16
  __bf16* ap = att_part + (size_t)hg * ((size_t)B * L * S) +
               ((size_t)(b * 1024 + l0 + cl)) * 1024 + sw + g * 8;
  #pragma unroll
  for (int kt = 0; kt < 8; ++kt) {
    bf16x8 o;
    #pragma unroll
    for (int j = 0; j < 8; ++j) o[j] = (__bf16)(att_acc[kt][j] * 0.125f);
    *reinterpret_cast<bf16x8*>(ap + kt * 32) = o;
  }
}

// ---------------------------------------------------------------------------
// Kernel 3: fc  out = (sum of 4 out_part) @ fc_w^T + fc_b  (f32 out)
// ---------------------------------------------------------------------------
__global__ __launch_bounds__(256) void fc_kernel(
    const float* __restrict__ part, const float* __restrict__ fcw,
    const float* __restrict__ fcb, float* __restrict__ out)
{
  __shared__ __align__(16) __bf16 At[64][264];
  __shared__ __align__(16) __bf16 Wt[64][264];
  const int tid = threadIdx.x;
  const int m0 = blockIdx.y * 64, n0 = blockIdx.x * 64;
  const size_t PSZ = (size_t)B * L * 256;

  for (int i = tid; i < 4096; i += 256) {
    int row = i >> 6, c4 = (i & 63) << 2;
    size_t off = (size_t)(m0 + row) * 256 + c4;
    float4 s0 = *reinterpret_cast<const float4*>(part + off);
    float4 s1 = *reinterpret_cast<const float4*>(part + PSZ + off);
    float4 s2 = *reinterpret_cast<const float4*>(part + 2 * PSZ + off);
    float4 s3 = *reinterpret_cast<const float4*>(part + 3 * PSZ + off);
    float4 ww = *reinterpret_cast<const float4*>(fcw + (size_t)(n0 + row) * 256 + c4);
    us4 ap, wp;
    ap[0] = bfbits(s0.x + s1.x + s2.x + s3.x);
    ap[1] = bfbits(s0.y + s1.y + s2.y + s3.y);
    ap[2] = bfbits(s0.z + s1.z + s2.z + s3.z);
    ap[3] = bfbits(s0.w + s1.w + s2.w + s3.w);
    wp[0] = bfbits(ww.x); wp[1] = bfbits(ww.y); wp[2] = bfbits(ww.z); wp[3] = bfbits(ww.w);
    *reinterpret_cast<us4*>(&At[row][c4]) = ap;
    *reinterpret_cast<us4*>(&Wt[row][c4]) = wp;
  }
  __syncthreads();

  const int w = tid >> 6, lane = tid & 63;
  const int cl = lane & 15, g = lane >> 4;
  f32x4 zf = {0.f, 0.f, 0.f, 0.f};
  f32x4 acc[4] = {zf, zf, zf, zf};
  #pragma unroll
  for (int kk = 0; kk < 8; ++kk) {
    bf16x8 af = *reinterpret_cast<const bf16x8*>(&At[w * 16 + cl][kk * 32 + g * 8]);
    #pragma unroll
    for (int nt = 0; nt < 4; ++nt) {
      bf16x8 bfr = *reinterpret_cast<const bf16x8*>(&Wt[nt * 16 + cl][kk * 32 + g * 8]);
      acc[nt] = __builtin_amdgcn_mfma_f32_16x16x32_bf16(af, bfr, acc[nt], 0, 0, 0);
    }
  }
  #pragma unroll
  for (int nt = 0; nt < 4; ++nt) {
    int n = n0 + nt * 16 + cl;
    float bias = fcb[n];
    #pragma unroll
    for (int r = 0; r < 4; ++r)
      out[(size_t)(m0 + w * 16 + g * 4 + r) * 256 + n] = acc[nt][r] + bias;
  }
}

// ---------------------------------------------------------------------------
// Kernel 4: att_mean = sum of 4 bf16 partials -> f32
// ---------------------------------------------------------------------------
__global__ __launch_bounds__(256) void reduce_att_kernel(
    const __bf16* __restrict__ ap, float* __restrict__ am)
{
  const size_t APSZ = (size_t)B * L * S;
  size_t i = ((size_t)blockIdx.x * 256 + threadIdx.x) * 8;
  bf16x8 a = *reinterpret_cast<const bf16x8*>(ap + i);
  bf16x8 c = *reinterpret_cast<const bf16x8*>(ap + APSZ + i);
  bf16x8 d = *reinterpret_cast<const bf16x8*>(ap + 2 * APSZ + i);
  bf16x8 e = *reinterpret_cast<const bf16x8*>(ap + 3 * APSZ + i);
  float4 o0, o1;
  o0.x = ((float)a[0] + (float)c[0]) + ((float)d[0] + (float)e[0]);
  o0.y = ((float)a[1] + (float)c[1]) + ((float)d[1] + (float)e[1]);
  o0.z = ((float)a[2] + (float)c[2]) + ((float)d[2] + (float)e[2]);
  o0.w = ((float)a[3] + (float)c[3]) + ((float)d[3] + (float)e[3]);
  o1.x = ((float)a[4] + (float)c[4]) + ((float)d[4] + (float)e[4]);
  o1.y = ((float)a[5] + (float)c[5]) + ((float)d[5] + (float)e[5]);
  o1.z = ((float)a[6] + (float)c[6]) + ((float)d[6] + (float)e[6]);
  o1.w = ((float)a[7] + (float)c[7]) + ((float)d[7] + (float)e[7]);
  *reinterpret_cast<float4*>(am + i) = o0;
  *reinterpret_cast<float4*>(am + i + 4) = o1;
}

// ---------------------------------------------------------------------------
extern "C" void kernel_launch(void* const* d_in, const int* in_sizes, int n_in,
                              void* d_out, int out_size, void* d_ws, size_t ws_size,
                              hipStream_t stream) {
  const float* q    = (const float*)d_in[0];
  const float* k    = (const float*)d_in[1];
  const float* v    = (const float*)d_in[2];
  const int*   qid  = (const int*)d_in[3];
  const int*   kid  = (const int*)d_in[4];
  const float* mask = (const float*)d_in[5];
  const float* wqs  = (const float*)d_in[6];
  const float* wqo  = (const float*)d_in[7];
  const float* wks  = (const float*)d_in[8];
  const float* wko  = (const float*)d_in[9];
  const float* wv   = (const float*)d_in[10];
  const float* fcw  = (const float*)d_in[11];
  const float* fcb  = (const float*)d_in[12];

  char* ws = (char*)d_ws;
  const size_t ACT  = (size_t)B * L * 256 * sizeof(__bf16);   // 4 MB
  const size_t PSZB = (size_t)B * L * 256 * sizeof(float);    // 8 MB
  const size_t APSZB = (size_t)B * L * S * sizeof(__bf16);    // 16 MB
  __bf16* qs  = (__bf16*)(ws + 0 * ACT);
  __bf16* qo  = (__bf16*)(ws + 1 * ACT);
  __bf16* ksl = (__bf16*)(ws + 2 * ACT);
  __bf16* kol = (__bf16*)(ws + 3 * ACT);
  __bf16* vht = (__bf16*)(ws + 4 * ACT);
  float*  out_part = (float*)(ws + 5 * ACT);                  // 4 x 8 MB f32
  __bf16* att_part = (__bf16*)(ws + 5 * ACT + 4 * PSZB);      // 4 x 16 MB bf16
  __bf16* maskT    = (__bf16*)(ws + 5 * ACT + 4 * PSZB + 4 * APSZB); // 16.8 MB

  float* out0 = (float*)d_out;
  float* att_mean = out0 + (size_t)B * L * 256;

  prep_mask_kernel<<<dim3(16, 64, 8), 256, 0, stream>>>(mask, maskT);
  proj_kernel<<<dim3(4, 128, 5), 256, 0, stream>>>(q, k, v, wqs, wqo, wks, wko, wv,
                                                   qs, qo, ksl, kol, vht);
  attn_kernel<<<dim3(64, 8, 4), 256, 0, stream>>>(qs, qo, ksl, kol, vht, qid, kid, maskT,
                                                  out_part, att_part);
  fc_kernel<<<dim3(4, 128), 256, 0, stream>>>(out_part, fcw, fcb, out0);
  reduce_att_kernel<<<dim3(4096), 256, 0, stream>>>(att_part, att_mean);
}

// Round 6
// 282.311 us; speedup vs baseline: 1.0230x; 1.0230x over previous
//
#include <hip/hip_runtime.h>
#include <hip/hip_bf16.h>

typedef float f32x4 __attribute__((ext_vector_type(4)));
typedef __bf16 bf16x8 __attribute__((ext_vector_type(8)));
typedef unsigned short us4 __attribute__((ext_vector_type(4)));

constexpr int B = 8, L = 1024, S = 1024, H = 8;
constexpr float LOG2E = 1.4426950408889634f;
// 1/sqrt(32) * log2(e): exp(x) == exp2(x*log2e); folded into Q-scale and mask.
constexpr float SCALE_Q = 0.17677669529663687f * 1.4426950408889634f;

__device__ __forceinline__ unsigned short bfbits(float x) {
  return __builtin_bit_cast(unsigned short, (__bf16)x);
}
__device__ __forceinline__ float b2f(unsigned short u) {
  return __builtin_bit_cast(float, (unsigned int)u << 16);
}

// ---------------------------------------------------------------------------
// Kernel 0: maskT[b][lt][s][16] = mask[b][lt*16+r][s] * LOG2E, bf16.
// 16x64 tile transpose via LDS; coalesced f32 reads, coalesced 8B writes.
// ---------------------------------------------------------------------------
__global__ __launch_bounds__(256) void prep_mask_kernel(
    const float* __restrict__ mask, __bf16* __restrict__ maskT)
{
  __shared__ float tile[16][65];
  const int tid = threadIdx.x;
  const int sc = blockIdx.x, lt = blockIdx.y, b = blockIdx.z;
  const int s0 = sc * 64;
  const int q = tid >> 6, sl = tid & 63;
  #pragma unroll
  for (int rr = 0; rr < 4; ++rr) {
    int row = q * 4 + rr;
    tile[row][sl] = mask[((size_t)(b * 1024 + lt * 16 + row)) * 1024 + s0 + sl] * LOG2E;
  }
  __syncthreads();
  const int sl2 = tid >> 2, rq = (tid & 3) * 4;
  us4 o;
  #pragma unroll
  for (int j = 0; j < 4; ++j) o[j] = bfbits(tile[rq + j][sl2]);
  *reinterpret_cast<us4*>(maskT + (((size_t)(b * 64 + lt)) * 1024 + s0 + sl2) * 16 + rq) = o;
}

// ---------------------------------------------------------------------------
// Kernel 1: five projection GEMMs (M=8192,N=256,K=256), y = x@W^T, bf16 out.
// A,W staged via LDS (coalesced f32 loads, one-time bf16 convert).
//   z=0..3: [B,H,T,32]   (q_self*SCALE_Q, q_other*SCALE_Q, k_self, k_other)
//   z=4   : [B,H,S/32,32vd,32s] tiles (v, transposed via LDS)
// ---------------------------------------------------------------------------
__global__ __launch_bounds__(256) void proj_kernel(
    const float* __restrict__ q, const float* __restrict__ k, const float* __restrict__ v,
    const float* __restrict__ wqs, const float* __restrict__ wqo,
    const float* __restrict__ wks, const float* __restrict__ wko,
    const float* __restrict__ wv,
    __bf16* __restrict__ qs, __bf16* __restrict__ qo,
    __bf16* __restrict__ ksl, __bf16* __restrict__ kol,
    __bf16* __restrict__ vht)
{
  const int proj = blockIdx.z;
  const float* X; const float* W;
  if (proj == 0)      { X = q; W = wqs; }
  else if (proj == 1) { X = q; W = wqo; }
  else if (proj == 2) { X = k; W = wks; }
  else if (proj == 3) { X = k; W = wko; }
  else                { X = v; W = wv;  }

  __shared__ __align__(16) char smem[2 * 64 * 264 * 2];
  __bf16 (*At)[264] = (__bf16(*)[264])smem;
  __bf16 (*Wt)[264] = (__bf16(*)[264])(smem + 64 * 264 * 2);
  float  (*ct)[65]  = (float(*)[65])smem;   // aliases At; used only post-sync (proj==4)

  const int tid = threadIdx.x;
  const int m0 = blockIdx.y * 64, n0 = blockIdx.x * 64;

  for (int i = tid; i < 4096; i += 256) {
    int row = i >> 6, c4 = (i & 63) << 2;
    float4 a  = *reinterpret_cast<const float4*>(X + (size_t)(m0 + row) * 256 + c4);
    float4 ww = *reinterpret_cast<const float4*>(W + (size_t)(n0 + row) * 256 + c4);
    us4 ap, wp;
    ap[0] = bfbits(a.x);  ap[1] = bfbits(a.y);  ap[2] = bfbits(a.z);  ap[3] = bfbits(a.w);
    wp[0] = bfbits(ww.x); wp[1] = bfbits(ww.y); wp[2] = bfbits(ww.z); wp[3] = bfbits(ww.w);
    *reinterpret_cast<us4*>(&At[row][c4]) = ap;
    *reinterpret_cast<us4*>(&Wt[row][c4]) = wp;
  }
  __syncthreads();

  const int w = tid >> 6, lane = tid & 63;
  const int cl = lane & 15, g = lane >> 4;

  f32x4 zf = {0.f, 0.f, 0.f, 0.f};
  f32x4 acc[4] = {zf, zf, zf, zf};
  #pragma unroll
  for (int kk = 0; kk < 8; ++kk) {
    bf16x8 af = *reinterpret_cast<const bf16x8*>(&At[w * 16 + cl][kk * 32 + g * 8]);
    #pragma unroll
    for (int nt = 0; nt < 4; ++nt) {
      bf16x8 bfr = *reinterpret_cast<const bf16x8*>(&Wt[nt * 16 + cl][kk * 32 + g * 8]);
      acc[nt] = __builtin_amdgcn_mfma_f32_16x16x32_bf16(af, bfr, acc[nt], 0, 0, 0);
    }
  }
  if (proj < 2) {
    #pragma unroll
    for (int nt = 0; nt < 4; ++nt)
      #pragma unroll
      for (int r = 0; r < 4; ++r) acc[nt][r] *= SCALE_Q;
  }

  if (proj < 4) {
    __bf16* Y = (proj == 0) ? qs : (proj == 1) ? qo : (proj == 2) ? ksl : kol;
    #pragma unroll
    for (int nt = 0; nt < 4; ++nt) {
      int n = n0 + nt * 16 + cl;
      int h = n >> 5, hd = n & 31;
      #pragma unroll
      for (int r = 0; r < 4; ++r) {
        int m = m0 + w * 16 + g * 4 + r;
        int bb = m >> 10, t = m & 1023;
        Y[(((size_t)(bb * H + h)) * 1024 + t) * 32 + hd] = (__bf16)acc[nt][r];
      }
    }
  } else {
    __syncthreads();   // At/Wt dead; reuse as ct
    #pragma unroll
    for (int nt = 0; nt < 4; ++nt)
      #pragma unroll
      for (int r = 0; r < 4; ++r)
        ct[w * 16 + g * 4 + r][nt * 16 + cl] = acc[nt][r];
    __syncthreads();
    int n_local = tid >> 2;          // 0..63 (h*32+vd within n-block)
    int sc = (tid & 3) << 4;         // 0,16,32,48 s-chunk
    int n = n0 + n_local;
    int h = n >> 5, vd = n & 31;
    int bb = m0 >> 10;
    int sbase = m0 & 1023;
    int t32 = (sbase + sc) >> 5, off = (sbase + sc) & 31;
    __bf16* dst = vht + ((((size_t)(bb * H + h)) * 32 + t32)) * 1024 + vd * 32 + off;
    bf16x8 o0, o1;
    #pragma unroll
    for (int j = 0; j < 8; ++j) o0[j] = (__bf16)ct[sc + j][n_local];
    #pragma unroll
    for (int j = 0; j < 8; ++j) o1[j] = (__bf16)ct[sc + 8 + j][n_local];
    *reinterpret_cast<bf16x8*>(dst) = o0;
    *reinterpret_cast<bf16x8*>(dst + 8) = o1;
  }
}

// ---------------------------------------------------------------------------
// Kernel 2: agent-aware attention. Block = (b, 16 q-rows), ALL 8 heads.
// 8 waves of 64; wave w owns s in [w*128, w*128+128). One barrier per head.
// Logits in log2 domain (SCALE_Q and maskT carry log2e); p = exp2(lg).
// Unnormalized exp written bf16 to per-wave pbuf; normalization applied in
// the PV readback, which also accumulates att_mean (written f32 DIRECTLY —
// no partials, no reduce pass). Out written as 8 per-wave partials summed
// by fc's staging loop.
// ---------------------------------------------------------------------------
__global__ __launch_bounds__(512, 4) void attn_kernel(
    const __bf16* __restrict__ qs, const __bf16* __restrict__ qo,
    const __bf16* __restrict__ ksl, const __bf16* __restrict__ kol,
    const __bf16* __restrict__ vht,
    const int* __restrict__ qid, const int* __restrict__ kid,
    const __bf16* __restrict__ maskT,
    float* __restrict__ out_part, float* __restrict__ att_mean)
{
  const int b = blockIdx.y;
  const int lt = blockIdx.x;
  const int l0 = lt * 16;
  const int tid = threadIdx.x;
  const int w = tid >> 6, lane = tid & 63;
  const int cl = lane & 15, g = lane >> 4;
  const int sw = w * 128;

  // pad 140: row stride 280B = 70 dw (~6 mod 32) spreads PV-read bank starts
  __shared__ __align__(16) __bf16 pbuf[8][16][140];
  __shared__ float redsum[2][8][16];

  int qid_r[4];
  #pragma unroll
  for (int r = 0; r < 4; ++r) qid_r[r] = qid[b * L + l0 + g * 4 + r];
  int kid_st[8];
  #pragma unroll
  for (int st = 0; st < 8; ++st) kid_st[st] = kid[b * S + sw + st * 16 + cl];

  // coalesced maskT loads: 8 B/lane, wave covers contiguous 512 B per st
  us4 mreg[8];
  {
    const __bf16* mbase = maskT + ((size_t)(b * 64 + lt)) * 16384 + (size_t)(sw + cl) * 16 + g * 4;
    #pragma unroll
    for (int st = 0; st < 8; ++st)
      mreg[st] = *reinterpret_cast<const us4*>(mbase + st * 256);
  }

  f32x4 zf = {0.f, 0.f, 0.f, 0.f};
  float att_acc[4][8];
  #pragma unroll
  for (int kt = 0; kt < 4; ++kt)
    #pragma unroll
    for (int j = 0; j < 8; ++j) att_acc[kt][j] = 0.f;

  const size_t PSZ = (size_t)B * L * 256;

  for (int h = 0; h < H; ++h) {
    const int par = h & 1;
    const size_t hb = ((size_t)(b * H + h)) * 1024;

    bf16x8 qsf = *reinterpret_cast<const bf16x8*>(qs + (hb + l0 + cl) * 32 + g * 8);
    bf16x8 qof = *reinterpret_cast<const bf16x8*>(qo + (hb + l0 + cl) * 32 + g * 8);
    const __bf16* kb1 = ksl + (hb + sw) * 32;
    const __bf16* kb2 = kol + (hb + sw) * 32;

    float rsum[4] = {0.f, 0.f, 0.f, 0.f};
    #pragma unroll
    for (int st = 0; st < 8; ++st) {
      bf16x8 kf1 = *reinterpret_cast<const bf16x8*>(kb1 + st * 512 + cl * 32 + g * 8);
      bf16x8 kf2 = *reinterpret_cast<const bf16x8*>(kb2 + st * 512 + cl * 32 + g * 8);
      f32x4 as = __builtin_amdgcn_mfma_f32_16x16x32_bf16(qsf, kf1, zf, 0, 0, 0);
      f32x4 ao = __builtin_amdgcn_mfma_f32_16x16x32_bf16(qof, kf2, zf, 0, 0, 0);
      int kc = kid_st[st];
      #pragma unroll
      for (int r = 0; r < 4; ++r) {
        float lg = ((qid_r[r] == kc) ? as[r] : ao[r]) + b2f(mreg[st][r]);
        float p = __builtin_amdgcn_exp2f(fminf(lg, 86.0f));
        pbuf[w][g * 4 + r][st * 16 + cl] = (__bf16)p;
        rsum[r] += p;
      }
    }

    // row-sum across the 16 cl lanes of each g-group, then across 8 waves
    #pragma unroll
    for (int r = 0; r < 4; ++r) {
      float sv = rsum[r];
      sv += __shfl_xor(sv, 1); sv += __shfl_xor(sv, 2);
      sv += __shfl_xor(sv, 4); sv += __shfl_xor(sv, 8);
      rsum[r] = sv;
    }
    if (cl == 0) {
      #pragma unroll
      for (int r = 0; r < 4; ++r) redsum[par][w][g * 4 + r] = rsum[r];
    }
    __syncthreads();
    float zrow = 0.f;
    #pragma unroll
    for (int q8 = 0; q8 < 8; ++q8) zrow += redsum[par][q8][cl];
    float inv_cl = 1.0f / zrow;
    float invq[4];
    #pragma unroll
    for (int r = 0; r < 4; ++r) invq[r] = __shfl(inv_cl, g * 4 + r);

    // PV + att accumulation (reads own wave's pbuf only; no barrier needed)
    f32x4 oa0 = zf, oa1 = zf;
    const __bf16* vb = vht + ((size_t)(b * H + h)) * 32 * 1024 + (size_t)w * 4 * 1024;
    #pragma unroll
    for (int kt = 0; kt < 4; ++kt) {
      bf16x8 pa = *reinterpret_cast<const bf16x8*>(&pbuf[w][cl][kt * 32 + g * 8]);
      #pragma unroll
      for (int j = 0; j < 8; ++j) att_acc[kt][j] += (float)pa[j] * inv_cl;
      bf16x8 v0 = *reinterpret_cast<const bf16x8*>(vb + kt * 1024 + cl * 32 + g * 8);
      bf16x8 v1 = *reinterpret_cast<const bf16x8*>(vb + kt * 1024 + 512 + cl * 32 + g * 8);
      oa0 = __builtin_amdgcn_mfma_f32_16x16x32_bf16(pa, v0, oa0, 0, 0, 0);
      oa1 = __builtin_amdgcn_mfma_f32_16x16x32_bf16(pa, v1, oa1, 0, 0, 0);
    }
    float* op = out_part + (size_t)w * PSZ + ((size_t)(b * 1024 + l0)) * 256 + h * 32;
    #pragma unroll
    for (int r = 0; r < 4; ++r) {
      op[(size_t)(g * 4 + r) * 256 + cl]      = oa0[r] * invq[r];
      op[(size_t)(g * 4 + r) * 256 + cl + 16] = oa1[r] * invq[r];
    }
  }

  // att_mean (all 8 heads summed, /8) -> f32, written once, directly
  float* am = att_mean + ((size_t)(b * 1024 + l0 + cl)) * 1024 + sw + g * 8;
  #pragma unroll
  for (int kt = 0; kt < 4; ++kt) {
    float4 o0, o1;
    o0.x = att_acc[kt][0] * 0.125f; o0.y = att_acc[kt][1] * 0.125f;
    o0.z = att_acc[kt][2] * 0.125f; o0.w = att_acc[kt][3] * 0.125f;
    o1.x = att_acc[kt][4] * 0.125f; o1.y = att_acc[kt][5] * 0.125f;
    o1.z = att_acc[kt][6] * 0.125f; o1.w = att_acc[kt][7] * 0.125f;
    *reinterpret_cast<float4*>(am + kt * 32) = o0;
    *reinterpret_cast<float4*>(am + kt * 32 + 4) = o1;
  }
}

// ---------------------------------------------------------------------------
// Kernel 3: fc  out = (sum of 8 out_part) @ fc_w^T + fc_b  (f32 out)
// ---------------------------------------------------------------------------
__global__ __launch_bounds__(256) void fc_kernel(
    const float* __restrict__ part, const float* __restrict__ fcw,
    const float* __restrict__ fcb, float* __restrict__ out)
{
  __shared__ __align__(16) __bf16 At[64][264];
  __shared__ __align__(16) __bf16 Wt[64][264];
  const int tid = threadIdx.x;
  const int m0 = blockIdx.y * 64, n0 = blockIdx.x * 64;
  const size_t PSZ = (size_t)B * L * 256;

  for (int i = tid; i < 4096; i += 256) {
    int row = i >> 6, c4 = (i & 63) << 2;
    size_t off = (size_t)(m0 + row) * 256 + c4;
    float4 s0 = *reinterpret_cast<const float4*>(part + off);
    #pragma unroll
    for (int p = 1; p < 8; ++p) {
      float4 sp = *reinterpret_cast<const float4*>(part + (size_t)p * PSZ + off);
      s0.x += sp.x; s0.y += sp.y; s0.z += sp.z; s0.w += sp.w;
    }
    float4 ww = *reinterpret_cast<const float4*>(fcw + (size_t)(n0 + row) * 256 + c4);
    us4 ap, wp;
    ap[0] = bfbits(s0.x); ap[1] = bfbits(s0.y); ap[2] = bfbits(s0.z); ap[3] = bfbits(s0.w);
    wp[0] = bfbits(ww.x); wp[1] = bfbits(ww.y); wp[2] = bfbits(ww.z); wp[3] = bfbits(ww.w);
    *reinterpret_cast<us4*>(&At[row][c4]) = ap;
    *reinterpret_cast<us4*>(&Wt[row][c4]) = wp;
  }
  __syncthreads();

  const int w = tid >> 6, lane = tid & 63;
  const int cl = lane & 15, g = lane >> 4;
  f32x4 zf = {0.f, 0.f, 0.f, 0.f};
  f32x4 acc[4] = {zf, zf, zf, zf};
  #pragma unroll
  for (int kk = 0; kk < 8; ++kk) {
    bf16x8 af = *reinterpret_cast<const bf16x8*>(&At[w * 16 + cl][kk * 32 + g * 8]);
    #pragma unroll
    for (int nt = 0; nt < 4; ++nt) {
      bf16x8 bfr = *reinterpret_cast<const bf16x8*>(&Wt[nt * 16 + cl][kk * 32 + g * 8]);
      acc[nt] = __builtin_amdgcn_mfma_f32_16x16x32_bf16(af, bfr, acc[nt], 0, 0, 0);
    }
  }
  #pragma unroll
  for (int nt = 0; nt < 4; ++nt) {
    int n = n0 + nt * 16 + cl;
    float bias = fcb[n];
    #pragma unroll
    for (int r = 0; r < 4; ++r)
      out[(size_t)(m0 + w * 16 + g * 4 + r) * 256 + n] = acc[nt][r] + bias;
  }
}

// ---------------------------------------------------------------------------
extern "C" void kernel_launch(void* const* d_in, const int* in_sizes, int n_in,
                              void* d_out, int out_size, void* d_ws, size_t ws_size,
                              hipStream_t stream) {
  const float* q    = (const float*)d_in[0];
  const float* k    = (const float*)d_in[1];
  const float* v    = (const float*)d_in[2];
  const int*   qid  = (const int*)d_in[3];
  const int*   kid  = (const int*)d_in[4];
  const float* mask = (const float*)d_in[5];
  const float* wqs  = (const float*)d_in[6];
  const float* wqo  = (const float*)d_in[7];
  const float* wks  = (const float*)d_in[8];
  const float* wko  = (const float*)d_in[9];
  const float* wv   = (const float*)d_in[10];
  const float* fcw  = (const float*)d_in[11];
  const float* fcb  = (const float*)d_in[12];

  char* ws = (char*)d_ws;
  const size_t ACT  = (size_t)B * L * 256 * sizeof(__bf16);   // 4 MB
  const size_t PSZB = (size_t)B * L * 256 * sizeof(float);    // 8 MB
  __bf16* qs  = (__bf16*)(ws + 0 * ACT);
  __bf16* qo  = (__bf16*)(ws + 1 * ACT);
  __bf16* ksl = (__bf16*)(ws + 2 * ACT);
  __bf16* kol = (__bf16*)(ws + 3 * ACT);
  __bf16* vht = (__bf16*)(ws + 4 * ACT);
  float*  out_part = (float*)(ws + 5 * ACT);                  // 8 x 8 MB f32
  __bf16* maskT    = (__bf16*)(ws + 5 * ACT + 8 * PSZB);      // 16.8 MB

  float* out0 = (float*)d_out;
  float* att_mean = out0 + (size_t)B * L * 256;

  prep_mask_kernel<<<dim3(16, 64, 8), 256, 0, stream>>>(mask, maskT);
  proj_kernel<<<dim3(4, 128, 5), 256, 0, stream>>>(q, k, v, wqs, wqo, wks, wko, wv,
                                                   qs, qo, ksl, kol, vht);
  attn_kernel<<<dim3(64, 8), 512, 0, stream>>>(qs, qo, ksl, kol, vht, qid, kid, maskT,
                                               out_part, att_mean);
  fc_kernel<<<dim3(4, 128), 256, 0, stream>>>(out_part, fcw, fcb, out0);
}